// Round 1
// 745.028 us; speedup vs baseline: 1.0157x; 1.0157x over previous
//
#include <hip/hip_runtime.h>

#define NC 512   // N_CLUSTERS

// ===========================================================================
// Pre-pass: dstT[w][s] = (u16)src[s][w]  (transpose verified R3/R5/R6).
// ===========================================================================
__global__ __launch_bounds__(256) void k_transpose_pack(
    const int* __restrict__ src, unsigned short* __restrict__ dst)
{
    __shared__ unsigned short tile[64][65];
    int tx = blockIdx.x % 8, ty = blockIdx.x / 8;
    int lane = threadIdx.x & 63, grp = threadIdx.x >> 6;
    for (int r = grp * 16; r < grp * 16 + 16; ++r)
        tile[r][lane] = (unsigned short)src[(ty * 64 + r) * NC + tx * 64 + lane];
    __syncthreads();
    for (int r = grp * 16; r < grp * 16 + 16; ++r)
        dst[(tx * 64 + r) * NC + ty * 64 + lane] = tile[lane][r];
}

// ===========================================================================
// Stage 1: discretize -> u16 symbols (verified R1/R5/R6).
// ===========================================================================
__global__ __launch_bounds__(256) void k_discretize(
    const float* __restrict__ x, const float* __restrict__ cent,
    unsigned short* __restrict__ out)
{
    __shared__ float c[NC];
    int tid = threadIdx.x;
    for (int i = tid; i < NC; i += 256) c[i] = cent[i];
    __syncthreads();
    int id = blockIdx.x * 256 + tid;   // 131072 exact
    float px = x[id];
    float best = fabsf(px - c[0]);
    int bi = 0;
    for (int k = 1; k < NC; ++k) {
        float d = fabsf(px - c[k]);
        if (d < best) { best = d; bi = k; }
    }
    out[id] = (unsigned short)bi;
}

// ===========================================================================
// Nibble-bin pop-min scanner (logic verified R4; insert() de-atomicized for
// redundant-lane folds: 4 lanes same addr/value plain RMW => net +1).
// 512 bins packed 8/word; window = 4 VGPRs (32 bins) + nonzero mask.
// ===========================================================================
struct ScanN {
    uint32_t* base;    // instance's 64-word nibble-bin region
    uint32_t w[4];
    uint32_t mask;     // bit k <=> bin (chunk*32+k) nonzero
    int chunk;

    static __device__ inline uint32_t nz4b(uint32_t x) {   // byte-nonzero -> 4 bits
        uint32_t y = (x & 0x7F7F7F7Fu) + 0x7F7F7F7Fu;
        y = (y | x) & 0x80808080u;
        return (y * 0x00204081u) >> 28;
    }
    static __device__ inline uint32_t spread4(uint32_t v) {
        v = (v | (v << 2)) & 0x33u;
        v = (v | (v << 1)) & 0x55u;
        return v;
    }
    static __device__ inline uint32_t nzn(uint32_t x) {    // per-nibble nonzero -> 8 bits
        uint32_t lo = x & 0x0F0F0F0Fu;
        uint32_t hi = (x >> 4) & 0x0F0F0F0Fu;
        return spread4(nz4b(lo)) | (spread4(nz4b(hi)) << 1);
    }
    __device__ inline void init(uint32_t* b) { base = b; mask = 0; chunk = -1; }
    __device__ inline void load() {
        uint4 a = *(const uint4*)(base + chunk * 4);   // 16B-aligned (stride 68 wds)
        w[0] = a.x; w[1] = a.y; w[2] = a.z; w[3] = a.w;
        mask = nzn(w[0]) | (nzn(w[1]) << 8) | (nzn(w[2]) << 16) | (nzn(w[3]) << 24);
    }
    __device__ inline void ensure() { while (mask == 0) { ++chunk; load(); } }
    __device__ inline int  peek()   { ensure(); return chunk * 32 + (int)__builtin_ctz(mask); }
    __device__ inline void consume_min() {          // precondition: mask != 0
        int k = (int)__builtin_ctz(mask);
        int dw = k >> 3, sh = (k & 7) << 2;
        uint32_t cnt = 0;
#pragma unroll
        for (int i = 0; i < 4; ++i) if (i == dw) { cnt = (w[i] >> sh) & 0xFu; w[i] -= (1u << sh); }
        if (cnt == 1) mask &= ~(1u << k);
    }
    __device__ inline int pop() { int v = peek(); consume_min(); return v; }
    __device__ inline void insert(int v) {          // precondition: v >= chunk*32
        int rel = v - chunk * 32;
        if (rel < 32) {
            int dw = rel >> 3, sh = (rel & 7) << 2;
#pragma unroll
            for (int i = 0; i < 4; ++i) if (i == dw) w[i] += (1u << sh);
            mask |= (1u << rel);
        } else {
            // plain RMW: redundant lanes read same old, write same new => +1 once
            uint32_t old = base[v >> 3];
            base[v >> 3] = old + (1u << ((v & 7) << 2));
        }
    }
};

// ===========================================================================
// Cooperative symbolic conv, _conv_reduce semantics (fold logic verified
// R1/R2/R5; nibble bins verified R4). 64-thread block = 16 instances x 4
// lanes.
//
// FOLD RESTRUCTURE (this round): load-to-load pipeline. Maintain the two
// smallest remaining values (u, v) in registers; with b = third smallest,
//   t'  = min(t2, v)
//   u'  = (t2<=v) ? v : min(t2, b)        (= next popped x)
//   v'  = (t2> b) ? pop(bins+{t2}) : b
// Only ~5 VALU ops sit between the arrival of t2 and the issue of the next
// add_lut load; the pq refill pop and the rare insert+pop run during the
// load's flight. Pure reordering of identical ops => bit-exact.
// Pop budget: 3 initial + 1 refill/iter over j=1..N-3 empties bins exactly;
// case-C insert+pop is net 0 (insert precedes pop, never pops empty).
// ===========================================================================
template<typename IT, typename OT, int CIN, int CO, int IH, int IW, int OH, int OW>
__device__ __forceinline__ void conv_body(
    const IT* __restrict__ in_sym,              // (B, IH, IW, CIN)
    const int* __restrict__ wsym,               // (25*CIN, CO)
    const unsigned short* __restrict__ convT,   // (NC, NC) [w][s]
    const int* __restrict__ add_lut,            // (NC, NC)
    const int* __restrict__ bias_lut,           // (NC, CO)
    const int* __restrict__ relu_lut,           // (NC,)
    OT* __restrict__ out)                       // (B, OH, OW, CO)
{
    constexpr int N    = 25 * CIN;
    constexpr int PPI  = OH * OW;
    constexpr int BPC  = (128 * PPI) / 16;      // blocks per co (exact)
    constexpr int STR  = 68;                    // words/instance (272B, 16B-aligned, bank-staggered)
    __shared__ __align__(16) uint32_t bins[16 * STR];   // 4.4 KB
    int tid = threadIdx.x;
    int il  = tid >> 2;                         // instance-in-block 0..15
    int sub = tid & 3;                          // redundancy/role index

    for (int i = tid; i < 16 * STR; i += 64) bins[i] = 0u;

    int posg = blockIdx.x % BPC;
    int co   = blockIdx.x / BPC;                // wave-uniform
    int pos  = posg * 16 + il;
    int b  = pos / PPI;
    int yx = pos % PPI;
    int oy = yx / OW, ox = yx % OW;

    uint32_t* mybins = bins + il * STR;
    __syncthreads();                            // bins zeroed (in-wave DS order anyway)

    for (int n = sub; n < N; n += 4) {          // 4 lanes split the N items
        int i   = n / (5 * CIN);
        int rem = n % (5 * CIN);
        int j   = rem / CIN;
        int c   = rem % CIN;
        int s = (int)in_sym[((b * IH + (oy * 2 + i)) * IW + (ox * 2 + j)) * CIN + c];
        int w = wsym[n * CO + co];              // <=4 distinct per wave-instr
        int g = convT[w * NC + s];              // <=4 distinct 1KB rows
        atomicAdd(&mybins[g >> 3], 1u << ((g & 7) << 2));
    }
    __syncthreads();                            // build visible before fold

    // Fold: all 4 lanes of an instance run the identical chain (lockstep).
    ScanN sc; sc.init(mybins);
    int t = sc.pop();
    int u = sc.pop();
    int v = sc.pop();
    int t2 = add_lut[u * NC + t];               // load for j=1
#pragma unroll 1
    for (int j = 1; j <= N - 3; ++j) {
        int bb = sc.pop();                      // refill: overlaps in-flight load
        bool cA = (t2 <= v);                    // t2 arrives here (vmcnt wait)
        bool cC = (t2 > bb);                    // cC implies !cA (v <= bb)
        t = cA ? t2 : v;
        u = cA ? v : (cC ? bb : t2);
        int t2n = add_lut[u * NC + t];          // issue next load ASAP
        if (cC) { sc.insert(t2); v = sc.pop(); }   // hidden under next load
        else    v = bb;
        t2 = t2n;
    }
    t = t2;                                     // j = N-2
    t = add_lut[v * NC + t];                    // j = N-1
    if (sub == 0)
        out[pos * CO + co] = (OT)relu_lut[bias_lut[t * CO + co]];
}

__global__ __launch_bounds__(64) void k_conv1(
    const unsigned short* in, const int* wsym, const unsigned short* convT,
    const int* add_lut, const int* bias, const int* relu, unsigned short* out)
{
    conv_body<unsigned short, unsigned short, 1, 6, 32, 32, 14, 14>(
        in, wsym, convT, add_lut, bias, relu, out);
}

__global__ __launch_bounds__(64) void k_conv2(
    const unsigned short* in, const int* wsym, const unsigned short* convT,
    const int* add_lut, const int* bias, const int* relu, int* out)
{
    conv_body<unsigned short, int, 6, 16, 14, 14, 5, 5>(
        in, wsym, convT, add_lut, bias, relu, out);
}

// ===========================================================================
// Cooperative symbolic FC, _fc_reduce = ascending pops (verified R1/R2).
// Block = one m (uniform) x 16 batch rows x 4 lanes. fcT rows <=4 distinct.
// PERM: fc1 reads c2o (b,5,5,16) with the (0,3,1,2)-flatten map (verified).
// Non-PERM reads the previous FC's m-major output [k][128+b].
// FOLD RESTRUCTURE: pops are chain-independent => pop next x while the
// current add_lut load is in flight. Critical path = load + addr only.
// ===========================================================================
template<int M, int K, bool PERM>
__device__ __forceinline__ void fc_body(
    const int* __restrict__ in_sym,
    const int* __restrict__ wsym,      // (M, K)
    const unsigned short* __restrict__ fcT,  // (NC, NC) [w][x]
    const int* __restrict__ add_lut,   // (NC, NC)
    const int* __restrict__ bias_lut,  // (NC, M)
    const int* __restrict__ relu_lut,  // (NC,)
    int* __restrict__ out)             // (M, 128) m-major
{
    constexpr int STR = 68;
    __shared__ __align__(16) uint32_t bins[16 * STR];   // 4.4 KB
    int tid = threadIdx.x;
    int il  = tid >> 2;
    int sub = tid & 3;

    for (int i = tid; i < 16 * STR; i += 64) bins[i] = 0u;

    int m  = blockIdx.x / 8;                   // wave-uniform
    int bg = blockIdx.x % 8;
    int b  = bg * 16 + il;

    uint32_t* mybins = bins + il * STR;
    __syncthreads();

    for (int k = sub; k < K; k += 4) {
        int xaddr;
        if (PERM) { int c = k / 25, yx = k % 25; xaddr = b * 400 + yx * 16 + c; }
        else      { xaddr = k * 128 + b; }
        int x = in_sym[xaddr];
        int w = wsym[m * K + k];               // <=4 distinct per wave-instr
        int g = fcT[w * NC + x];               // <=4 distinct rows
        atomicAdd(&mybins[g >> 3], 1u << ((g & 7) << 2));
    }
    __syncthreads();

    // Pipelined ascending-pop fold: pop s+1 during load s.
    ScanN sc; sc.init(mybins);
    int t = sc.pop();
    int x = sc.pop();
    int t2 = add_lut[x * NC + t];              // load s=1
#pragma unroll 1
    for (int s = 1; s < K - 1; ++s) {
        int xn = sc.pop();                     // overlaps in-flight load
        t = t2;                                // vmcnt wait lands here
        t2 = add_lut[xn * NC + t];             // issue next load
    }
    t = t2;
    if (sub == 0)
        out[m * 128 + b] = relu_lut[bias_lut[t * M + m]];
}

__global__ __launch_bounds__(64) void k_fc1(
    const int* in, const int* wsym, const unsigned short* fcT,
    const int* add_lut, const int* bias, const int* relu, int* out)
{
    fc_body<120, 400, true>(in, wsym, fcT, add_lut, bias, relu, out);
}

__global__ __launch_bounds__(64) void k_fc2(
    const int* in, const int* wsym, const unsigned short* fcT,
    const int* add_lut, const int* bias, const int* relu, int* out)
{
    fc_body<84, 120, false>(in, wsym, fcT, add_lut, bias, relu, out);
}

// ===========================================================================
// Head: feats = centroid[sym], logits @ W^T + b, softmax. Reads m-major f2.
// ===========================================================================
__global__ __launch_bounds__(64) void k_head(
    const int* __restrict__ f2m,       // (84, 128) m-major
    const float* __restrict__ cent,    // (NC,)
    const float* __restrict__ w,       // (10, 84)
    const float* __restrict__ bias,    // (10,)
    float* __restrict__ out)           // (128, 10)
{
    int b = blockIdx.x * 64 + threadIdx.x;
    float acc[10];
#pragma unroll
    for (int o = 0; o < 10; ++o) acc[o] = bias[o];
    for (int k = 0; k < 84; ++k) {
        float f = cent[f2m[k * 128 + b]];      // coalesced
#pragma unroll
        for (int o = 0; o < 10; ++o) acc[o] += f * w[o * 84 + k];
    }
    float mx = acc[0];
#pragma unroll
    for (int o = 1; o < 10; ++o) mx = fmaxf(mx, acc[o]);
    float s = 0.f;
#pragma unroll
    for (int o = 0; o < 10; ++o) { acc[o] = expf(acc[o] - mx); s += acc[o]; }
    float inv = 1.f / s;
#pragma unroll
    for (int o = 0; o < 10; ++o) out[b * 10 + o] = acc[o] * inv;
}

// ===========================================================================
extern "C" void kernel_launch(void* const* d_in, const int* in_sizes, int n_in,
                              void* d_out, int out_size, void* d_ws, size_t ws_size,
                              hipStream_t stream)
{
    const float* x_bat  = (const float*)d_in[0];
    const float* cent   = (const float*)d_in[1];
    const int* conv_lut = (const int*)d_in[2];
    const int* fc_lut   = (const int*)d_in[3];
    const int* add_lut  = (const int*)d_in[4];
    const int* relu_lut = (const int*)d_in[5];
    const int* c1_bias  = (const int*)d_in[6];
    const int* c2_bias  = (const int*)d_in[7];
    const int* f1_bias  = (const int*)d_in[8];
    const int* f2_bias  = (const int*)d_in[9];
    const int* c1f      = (const int*)d_in[10];
    const int* c2f      = (const int*)d_in[11];
    const int* f1f      = (const int*)d_in[12];
    const int* f2f      = (const int*)d_in[13];
    const float* fc3_w  = (const float*)d_in[14];
    const float* fc3_b  = (const float*)d_in[15];
    float* out = (float*)d_out;

    char* ws = (char*)d_ws;
    unsigned short* convT = (unsigned short*)(ws);            // 512 KB
    unsigned short* fcT   = (unsigned short*)(ws + 524288);   // 512 KB
    unsigned short* sym0  = (unsigned short*)(ws + 1048576);  // 256 KB
    unsigned short* c1o   = (unsigned short*)(ws + 1310720);  // 294 KB (b,14,14,6) u16
    int* c2o = (int*)(ws + 1611776);                          // 200 KB (b,5,5,16)
    int* f1o = (int*)(ws + 1816576);                          //  60 KB (120,128) m-major
    int* f2o = (int*)(ws + 1878016);                          //  42 KB (84,128)  m-major
    // peak ws ~1.92 MB (< R3's proven 2.29 MB)

    k_transpose_pack<<<64, 256, 0, stream>>>(conv_lut, convT);
    k_transpose_pack<<<64, 256, 0, stream>>>(fc_lut, fcT);
    k_discretize<<<512, 256, 0, stream>>>(x_bat, cent, sym0);
    // conv1: 6 co x 1568 pos-groups = 9408 blocks (16 inst each)
    k_conv1<<<9408, 64, 0, stream>>>(sym0, c1f, convT, add_lut, c1_bias, relu_lut, c1o);
    // conv2: 16 co x 200 pos-groups = 3200 blocks
    k_conv2<<<3200, 64, 0, stream>>>(c1o, c2f, convT, add_lut, c2_bias, relu_lut, c2o);
    // fc1: 120 m x 8 b-groups = 960 blocks
    k_fc1<<<960, 64, 0, stream>>>(c2o, f1f, fcT, add_lut, f1_bias, relu_lut, f1o);
    // fc2: 84 m x 8 b-groups = 672 blocks
    k_fc2<<<672, 64, 0, stream>>>(f1o, f2f, fcT, add_lut, f2_bias, relu_lut, f2o);
    k_head<<<2, 64, 0, stream>>>(f2o, cent, fc3_w, fc3_b, out);
}

// Round 2
// 373.737 us; speedup vs baseline: 2.0247x; 1.9935x over previous
//
#include <hip/hip_runtime.h>

#define NC 512   // N_CLUSTERS

// ===========================================================================
// Pre-pass: dstT[w][s] = (u16)src[s][w]  (transpose verified R3/R5/R6).
// ===========================================================================
__global__ __launch_bounds__(256) void k_transpose_pack(
    const int* __restrict__ src, unsigned short* __restrict__ dst)
{
    __shared__ unsigned short tile[64][65];
    int tx = blockIdx.x % 8, ty = blockIdx.x / 8;
    int lane = threadIdx.x & 63, grp = threadIdx.x >> 6;
    for (int r = grp * 16; r < grp * 16 + 16; ++r)
        tile[r][lane] = (unsigned short)src[(ty * 64 + r) * NC + tx * 64 + lane];
    __syncthreads();
    for (int r = grp * 16; r < grp * 16 + 16; ++r)
        dst[(tx * 64 + r) * NC + ty * 64 + lane] = tile[lane][r];
}

// ===========================================================================
// Stage 1: discretize -> u16 symbols (verified R1/R5/R6).
// ===========================================================================
__global__ __launch_bounds__(256) void k_discretize(
    const float* __restrict__ x, const float* __restrict__ cent,
    unsigned short* __restrict__ out)
{
    __shared__ float c[NC];
    int tid = threadIdx.x;
    for (int i = tid; i < NC; i += 256) c[i] = cent[i];
    __syncthreads();
    int id = blockIdx.x * 256 + tid;   // 131072 exact
    float px = x[id];
    float best = fabsf(px - c[0]);
    int bi = 0;
    for (int k = 1; k < NC; ++k) {
        float d = fabsf(px - c[k]);
        if (d < best) { best = d; bi = k; }
    }
    out[id] = (unsigned short)bi;
}

// ===========================================================================
// Nibble-bin pop-min scanner v2 (logic verified R4; R2: incremental window
// masks in LDS + u64 window regs).
// Layout per instance (STR=84 words): [0..63] nibble-count words (8 bins/wd),
// [64..79] per-window nonzero-nibble masks, [80..83] pad (16B align + bank
// stagger). Masks are maintained by build atomicOr + far-insert RMW; a
// window is loaded exactly once (chunk monotone, inserts never target past
// windows), so the stored mask is exact at load time. Reload = 2 LDS reads,
// no nzn() bit-twiddle (was ~86 VALU at wave level, ~1.7x/iter).
// ===========================================================================
struct ScanN {
    uint32_t* base;    // instance's 84-word region
    uint64_t w0, w1;   // current 32-bin window (128b of nibble counts)
    uint32_t mask;     // bit k <=> bin (chunk*32+k) nonzero
    int chunk;

    __device__ inline void init(uint32_t* b) { base = b; mask = 0; chunk = -1; }
    __device__ inline void load() {
        uint4 a = *(const uint4*)(base + chunk * 4);   // 16B-aligned
        mask = base[64 + chunk];                        // precomputed mask
        w0 = ((uint64_t)a.y << 32) | a.x;
        w1 = ((uint64_t)a.w << 32) | a.z;
    }
    __device__ inline void ensure() { while (mask == 0) { ++chunk; load(); } }
    __device__ inline int  peek()   { ensure(); return chunk * 32 + (int)__builtin_ctz(mask); }
    __device__ inline void consume_min() {          // precondition: mask != 0
        int k = (int)__builtin_ctz(mask);
        int sh = (k & 15) << 2;
        bool hi = k >= 16;
        uint64_t cw = hi ? w1 : w0;
        uint32_t cnt = (uint32_t)(cw >> sh) & 0xFu;
        cw -= (1ull << sh);
        if (hi) w1 = cw; else w0 = cw;
        if (cnt == 1) mask &= ~(1u << k);
    }
    __device__ inline int pop() { int v = peek(); consume_min(); return v; }
    __device__ inline void insert(int v) {          // precondition: v >= chunk*32
        int rel = v - chunk * 32;
        if (rel < 32) {
            int sh = (rel & 15) << 2;
            bool hi = rel >= 16;
            uint64_t cw = hi ? w1 : w0;
            cw += (1ull << sh);
            if (hi) w1 = cw; else w0 = cw;
            mask |= (1u << rel);
        } else {
            // plain RMW: redundant lanes read same old, write same new
            uint32_t old = base[v >> 3];
            base[v >> 3] = old + (1u << ((v & 7) << 2));
            uint32_t om = base[64 + (v >> 5)];
            base[64 + (v >> 5)] = om | (1u << (v & 31));
        }
    }
};

// ===========================================================================
// Cooperative symbolic conv, _conv_reduce semantics (fold logic verified
// R1/R2/R5 + last-round bit-exact restructure; nibble bins verified R4).
// 64-thread block = 16 instances x 4 lanes. Load-to-load pipelined fold with
// sched_barrier(0) pinning the add_lut issue above the pq work.
// ===========================================================================
template<typename IT, typename OT, int CIN, int CO, int IH, int IW, int OH, int OW>
__device__ __forceinline__ void conv_body(
    const IT* __restrict__ in_sym,              // (B, IH, IW, CIN)
    const int* __restrict__ wsym,               // (25*CIN, CO)
    const unsigned short* __restrict__ convT,   // (NC, NC) [w][s]
    const int* __restrict__ add_lut,            // (NC, NC)
    const int* __restrict__ bias_lut,           // (NC, CO)
    const int* __restrict__ relu_lut,           // (NC,)
    OT* __restrict__ out)                       // (B, OH, OW, CO)
{
    constexpr int N    = 25 * CIN;
    constexpr int PPI  = OH * OW;
    constexpr int BPC  = (128 * PPI) / 16;      // blocks per co (exact)
    constexpr int STR  = 84;                    // words/instance (336B, 16B-aligned)
    __shared__ __align__(16) uint32_t bins[16 * STR];   // 5.4 KB
    int tid = threadIdx.x;
    int il  = tid >> 2;                         // instance-in-block 0..15
    int sub = tid & 3;                          // redundancy/role index

    for (int i = tid; i < 16 * STR; i += 64) bins[i] = 0u;

    int posg = blockIdx.x % BPC;
    int co   = blockIdx.x / BPC;                // wave-uniform
    int pos  = posg * 16 + il;
    int b  = pos / PPI;
    int yx = pos % PPI;
    int oy = yx / OW, ox = yx % OW;

    uint32_t* mybins = bins + il * STR;
    __syncthreads();                            // bins zeroed

    for (int n = sub; n < N; n += 4) {          // 4 lanes split the N items
        int i   = n / (5 * CIN);
        int rem = n % (5 * CIN);
        int j   = rem / CIN;
        int c   = rem % CIN;
        int s = (int)in_sym[((b * IH + (oy * 2 + i)) * IW + (ox * 2 + j)) * CIN + c];
        int w = wsym[n * CO + co];              // <=4 distinct per wave-instr
        int g = convT[w * NC + s];              // <=4 distinct 1KB rows
        atomicAdd(&mybins[g >> 3], 1u << ((g & 7) << 2));
        atomicOr (&mybins[64 + (g >> 5)], 1u << (g & 31));   // window mask
    }
    __syncthreads();                            // build visible before fold

    // Fold: all 4 lanes of an instance run the identical chain (lockstep).
    // Pipelined: only selects+addr sit between t2 arrival and next issue;
    // refill pop + rare insert/pop run during the load's flight.
    ScanN sc; sc.init(mybins);
    int t = sc.pop();
    int u = sc.pop();
    int v = sc.pop();
    int t2 = add_lut[u * NC + t];               // load for j=1
#pragma unroll 1
    for (int j = 1; j <= N - 3; ++j) {
        int bb = sc.pop();                      // refill: overlaps in-flight load
        bool cA = (t2 <= v);                    // t2 arrives here (vmcnt wait)
        bool cC = (t2 > bb);                    // cC implies !cA (v <= bb)
        t = cA ? t2 : v;
        u = cA ? v : (cC ? bb : t2);
        int t2n = add_lut[u * NC + t];          // issue next load ASAP
        __builtin_amdgcn_sched_barrier(0);      // pin load above pq work
        if (cC) { sc.insert(t2); v = sc.pop(); }   // hidden under next load
        else    v = bb;
        t2 = t2n;
    }
    t = t2;                                     // j = N-2
    t = add_lut[v * NC + t];                    // j = N-1
    if (sub == 0)
        out[pos * CO + co] = (OT)relu_lut[bias_lut[t * CO + co]];
}

__global__ __launch_bounds__(64) void k_conv1(
    const unsigned short* in, const int* wsym, const unsigned short* convT,
    const int* add_lut, const int* bias, const int* relu, unsigned short* out)
{
    conv_body<unsigned short, unsigned short, 1, 6, 32, 32, 14, 14>(
        in, wsym, convT, add_lut, bias, relu, out);
}

__global__ __launch_bounds__(64) void k_conv2(
    const unsigned short* in, const int* wsym, const unsigned short* convT,
    const int* add_lut, const int* bias, const int* relu, int* out)
{
    conv_body<unsigned short, int, 6, 16, 14, 14, 5, 5>(
        in, wsym, convT, add_lut, bias, relu, out);
}

// ===========================================================================
// Cooperative symbolic FC, _fc_reduce = ascending pops (verified R1/R2).
// R2: block = one m (uniform) x 8 batch rows x 8 lanes -> 2x blocks (fc1
// 1920, fc2 1344) for latency hiding on the long serial chains; build split
// 8 ways. fcT rows <=8 distinct per wave-instr.
// PERM: fc1 reads c2o (b,5,5,16) with the (0,3,1,2)-flatten map (verified).
// Non-PERM reads the previous FC's m-major output [k][128+b].
// ===========================================================================
template<int M, int K, bool PERM>
__device__ __forceinline__ void fc_body(
    const int* __restrict__ in_sym,
    const int* __restrict__ wsym,      // (M, K)
    const unsigned short* __restrict__ fcT,  // (NC, NC) [w][x]
    const int* __restrict__ add_lut,   // (NC, NC)
    const int* __restrict__ bias_lut,  // (NC, M)
    const int* __restrict__ relu_lut,  // (NC,)
    int* __restrict__ out)             // (M, 128) m-major
{
    constexpr int STR = 84;
    __shared__ __align__(16) uint32_t bins[8 * STR];   // 2.7 KB
    int tid = threadIdx.x;
    int il  = tid >> 3;                        // instance 0..7
    int sub = tid & 7;

    for (int i = tid; i < 8 * STR; i += 64) bins[i] = 0u;

    int m  = blockIdx.x / 16;                  // wave-uniform
    int bg = blockIdx.x % 16;
    int b  = bg * 8 + il;

    uint32_t* mybins = bins + il * STR;
    __syncthreads();

    for (int k = sub; k < K; k += 8) {
        int xaddr;
        if (PERM) { int c = k / 25, yx = k % 25; xaddr = b * 400 + yx * 16 + c; }
        else      { xaddr = k * 128 + b; }
        int x = in_sym[xaddr];
        int w = wsym[m * K + k];               // <=8 distinct per wave-instr
        int g = fcT[w * NC + x];               // <=8 distinct rows
        atomicAdd(&mybins[g >> 3], 1u << ((g & 7) << 2));
        atomicOr (&mybins[64 + (g >> 5)], 1u << (g & 31));   // window mask
    }
    __syncthreads();

    // Pipelined ascending-pop fold: pop s+1 during load s.
    ScanN sc; sc.init(mybins);
    int t = sc.pop();
    int x = sc.pop();
    int t2 = add_lut[x * NC + t];              // load s=1
#pragma unroll 1
    for (int s = 1; s < K - 1; ++s) {
        int xn = sc.pop();                     // overlaps in-flight load
        t = t2;                                // vmcnt wait lands here
        t2 = add_lut[xn * NC + t];             // issue next load
        __builtin_amdgcn_sched_barrier(0);     // pin load issue in-loop
    }
    t = t2;
    if (sub == 0)
        out[m * 128 + b] = relu_lut[bias_lut[t * M + m]];
}

__global__ __launch_bounds__(64) void k_fc1(
    const int* in, const int* wsym, const unsigned short* fcT,
    const int* add_lut, const int* bias, const int* relu, int* out)
{
    fc_body<120, 400, true>(in, wsym, fcT, add_lut, bias, relu, out);
}

__global__ __launch_bounds__(64) void k_fc2(
    const int* in, const int* wsym, const unsigned short* fcT,
    const int* add_lut, const int* bias, const int* relu, int* out)
{
    fc_body<84, 120, false>(in, wsym, fcT, add_lut, bias, relu, out);
}

// ===========================================================================
// Head: feats = centroid[sym], logits @ W^T + b, softmax. Reads m-major f2.
// ===========================================================================
__global__ __launch_bounds__(64) void k_head(
    const int* __restrict__ f2m,       // (84, 128) m-major
    const float* __restrict__ cent,    // (NC,)
    const float* __restrict__ w,       // (10, 84)
    const float* __restrict__ bias,    // (10,)
    float* __restrict__ out)           // (128, 10)
{
    int b = blockIdx.x * 64 + threadIdx.x;
    float acc[10];
#pragma unroll
    for (int o = 0; o < 10; ++o) acc[o] = bias[o];
    for (int k = 0; k < 84; ++k) {
        float f = cent[f2m[k * 128 + b]];      // coalesced
#pragma unroll
        for (int o = 0; o < 10; ++o) acc[o] += f * w[o * 84 + k];
    }
    float mx = acc[0];
#pragma unroll
    for (int o = 1; o < 10; ++o) mx = fmaxf(mx, acc[o]);
    float s = 0.f;
#pragma unroll
    for (int o = 0; o < 10; ++o) { acc[o] = expf(acc[o] - mx); s += acc[o]; }
    float inv = 1.f / s;
#pragma unroll
    for (int o = 0; o < 10; ++o) out[b * 10 + o] = acc[o] * inv;
}

// ===========================================================================
extern "C" void kernel_launch(void* const* d_in, const int* in_sizes, int n_in,
                              void* d_out, int out_size, void* d_ws, size_t ws_size,
                              hipStream_t stream)
{
    const float* x_bat  = (const float*)d_in[0];
    const float* cent   = (const float*)d_in[1];
    const int* conv_lut = (const int*)d_in[2];
    const int* fc_lut   = (const int*)d_in[3];
    const int* add_lut  = (const int*)d_in[4];
    const int* relu_lut = (const int*)d_in[5];
    const int* c1_bias  = (const int*)d_in[6];
    const int* c2_bias  = (const int*)d_in[7];
    const int* f1_bias  = (const int*)d_in[8];
    const int* f2_bias  = (const int*)d_in[9];
    const int* c1f      = (const int*)d_in[10];
    const int* c2f      = (const int*)d_in[11];
    const int* f1f      = (const int*)d_in[12];
    const int* f2f      = (const int*)d_in[13];
    const float* fc3_w  = (const float*)d_in[14];
    const float* fc3_b  = (const float*)d_in[15];
    float* out = (float*)d_out;

    char* ws = (char*)d_ws;
    unsigned short* convT = (unsigned short*)(ws);            // 512 KB
    unsigned short* fcT   = (unsigned short*)(ws + 524288);   // 512 KB
    unsigned short* sym0  = (unsigned short*)(ws + 1048576);  // 256 KB
    unsigned short* c1o   = (unsigned short*)(ws + 1310720);  // 294 KB (b,14,14,6) u16
    int* c2o = (int*)(ws + 1611776);                          // 200 KB (b,5,5,16)
    int* f1o = (int*)(ws + 1816576);                          //  60 KB (120,128) m-major
    int* f2o = (int*)(ws + 1878016);                          //  42 KB (84,128)  m-major
    // peak ws ~1.92 MB (< R3's proven 2.29 MB)

    k_transpose_pack<<<64, 256, 0, stream>>>(conv_lut, convT);
    k_transpose_pack<<<64, 256, 0, stream>>>(fc_lut, fcT);
    k_discretize<<<512, 256, 0, stream>>>(x_bat, cent, sym0);
    // conv1: 6 co x 1568 pos-groups = 9408 blocks (16 inst each)
    k_conv1<<<9408, 64, 0, stream>>>(sym0, c1f, convT, add_lut, c1_bias, relu_lut, c1o);
    // conv2: 16 co x 200 pos-groups = 3200 blocks
    k_conv2<<<3200, 64, 0, stream>>>(c1o, c2f, convT, add_lut, c2_bias, relu_lut, c2o);
    // fc1: 120 m x 16 b-groups = 1920 blocks (8 inst x 8 lanes)
    k_fc1<<<1920, 64, 0, stream>>>(c2o, f1f, fcT, add_lut, f1_bias, relu_lut, f1o);
    // fc2: 84 m x 16 b-groups = 1344 blocks
    k_fc2<<<1344, 64, 0, stream>>>(f1o, f2f, fcT, add_lut, f2_bias, relu_lut, f2o);
    k_head<<<2, 64, 0, stream>>>(f2o, cent, fc3_w, fc3_b, out);
}